// Round 10
// baseline (1333.371 us; speedup 1.0000x reference)
//
#include <hip/hip_runtime.h>
#include <hip/hip_bf16.h>

// Shapes
#define BSZ 16
#define NSEG 64
#define NSEN 32
#define DM 1024
#define NH 8
#define DKH 128
#define DFF 2048

typedef short bf16x8 __attribute__((ext_vector_type(8)));
typedef float f32x4 __attribute__((ext_vector_type(4)));

__device__ __forceinline__ float b2f(short u) {
  union { unsigned int i; float f; } c;
  c.i = ((unsigned int)(unsigned short)u) << 16;
  return c.f;
}
__device__ __forceinline__ short f2b(float f) {
  __hip_bfloat16 h = __float2bfloat16(f);
  return *reinterpret_cast<short*>(&h);
}

#define SCHED0 __builtin_amdgcn_sched_barrier(0)
#define BAR do { SCHED0; __builtin_amdgcn_s_barrier(); SCHED0; } while (0)

// ================= fused prep: build_av + 5 weight transposes + LN =================
__device__ __forceinline__ void transpose_body(const float* __restrict__ W,
                                               short* __restrict__ Wt,
                                               int K, int N, int bx, int by,
                                               float* tile /*32*33*/) {
  int tx = threadIdx.x & 31, ty = threadIdx.x >> 5;
  int n0 = bx * 32, k0 = by * 32;
#pragma unroll
  for (int i = 0; i < 32; i += 8)
    tile[(ty + i) * 33 + tx] = W[(size_t)(k0 + ty + i) * N + n0 + tx];
  __syncthreads();
#pragma unroll
  for (int i = 0; i < 32; i += 8)
    Wt[(size_t)(n0 + ty + i) * K + k0 + tx] = f2b(tile[tx * 33 + ty + i]);
}

__global__ __launch_bounds__(256) void prep_kernel(
    const float* __restrict__ A, const float* __restrict__ V, short* __restrict__ avbf,
    const float* __restrict__ Wk, short* __restrict__ WkT,
    const float* __restrict__ Wv, short* __restrict__ WvT,
    const float* __restrict__ Wq, short* __restrict__ WqT,
    const float* __restrict__ W1, short* __restrict__ W1T,
    const float* __restrict__ W2, short* __restrict__ W2T,
    const float* __restrict__ S, const float* __restrict__ gamma,
    const float* __restrict__ beta, short* __restrict__ Snbf) {
  __shared__ float smem[32 * 33];
  int bid = blockIdx.x;
  int t = threadIdx.x;
  if (bid < 2048) {
    int i = bid * 256 + t;
    size_t o = (size_t)i * 4;
    int r = (int)(o >> 10);
    int d = (int)(o & 1023);
    int m = r & 1;
    int bseg = r >> 1;
    const float* src = (m ? V : A) + (size_t)bseg * 1024 + d;
    float4 v = *(const float4*)src;
    short4 out;
    out.x = f2b(v.x); out.y = f2b(v.y); out.z = f2b(v.z); out.w = f2b(v.w);
    *(short4*)(avbf + o) = out;
  } else if (bid < 3072) {
    int id = bid - 2048;
    transpose_body(Wk, WkT, 1024, 1024, id & 31, id >> 5, smem);
  } else if (bid < 4096) {
    int id = bid - 3072;
    transpose_body(Wv, WvT, 1024, 1024, id & 31, id >> 5, smem);
  } else if (bid < 5120) {
    int id = bid - 4096;
    transpose_body(Wq, WqT, 1024, 1024, id & 31, id >> 5, smem);
  } else if (bid < 7168) {
    int id = bid - 5120;
    transpose_body(W1, W1T, 1024, 2048, id & 63, id >> 6, smem);
  } else if (bid < 9216) {
    int id = bid - 7168;
    transpose_body(W2, W2T, 2048, 1024, id & 31, id >> 5, smem);
  } else {
    int row = bid - 9216;
    int l = t & 63, w = t >> 6;
    const float* x = S + (size_t)row * 1024;
    float4 v = ((const float4*)x)[t];
    float s = v.x + v.y + v.z + v.w;
#pragma unroll
    for (int off = 32; off; off >>= 1) s += __shfl_down(s, off);
    if (l == 0) smem[w] = s;
    __syncthreads();
    if (t == 0) smem[4] = (smem[0] + smem[1] + smem[2] + smem[3]) * (1.0f / 1024.0f);
    __syncthreads();
    float mean = smem[4];
    float4 c = {v.x - mean, v.y - mean, v.z - mean, v.w - mean};
    float s2 = c.x * c.x + c.y * c.y + c.z * c.z + c.w * c.w;
#pragma unroll
    for (int off = 32; off; off >>= 1) s2 += __shfl_down(s2, off);
    __syncthreads();
    if (l == 0) smem[w] = s2;
    __syncthreads();
    if (t == 0) smem[5] = (smem[0] + smem[1] + smem[2] + smem[3]) * (1.0f / 1024.0f);
    __syncthreads();
    float rstd = rsqrtf(smem[5] + 1e-5f);
    int base = t * 4;
    short4 o;
    o.x = f2b(c.x * rstd * gamma[base + 0] + beta[base + 0]);
    o.y = f2b(c.y * rstd * gamma[base + 1] + beta[base + 1]);
    o.z = f2b(c.z * rstd * gamma[base + 2] + beta[base + 2]);
    o.w = f2b(c.w * rstd * gamma[base + 3] + beta[base + 3]);
    *(short4*)(Snbf + (size_t)row * 1024 + base) = o;
  }
}

// ================ fused KV + Q projections (m97 128x128 body, K=1024) ================
__global__ __launch_bounds__(256) void gemm_kvq(const short* __restrict__ avbf,
                                                const short* __restrict__ WkvT,
                                                const float* __restrict__ bk,
                                                const float* __restrict__ bv,
                                                short* __restrict__ kbf,
                                                short* __restrict__ vbf,
                                                const short* __restrict__ Snbf,
                                                const short* __restrict__ WqT,
                                                const float* __restrict__ bq,
                                                short* __restrict__ qbf) {
  constexpr int BK = 32;
  __shared__ short As[128 * BK];
  __shared__ short Bs[128 * BK];
  int bid = blockIdx.x;
  const short *Ab, *Bb;
  const float *biasLo, *biasHi;
  short *Clo, *Chi;
  int bm, bn;
  bool split;
  if (bid < 256) {
    int nb = (bid & 7) * 32 + (bid >> 3);
    bn = nb & 15; bm = nb >> 4;
    Ab = avbf; Bb = WkvT; biasLo = bk; biasHi = bv; Clo = kbf; Chi = vbf; split = true;
  } else {
    int id = bid - 256;
    bm = id >> 3; bn = id & 7;
    Ab = Snbf; Bb = WqT; biasLo = bq; biasHi = bq; Clo = qbf; Chi = qbf; split = false;
  }

  const int t = threadIdx.x, w = t >> 6, l = t & 63;
  const int wm = w >> 1, wn = w & 1;
  f32x4 acc[4][4] = {};
  const size_t brow = (size_t)bm * 128, bcol = (size_t)bn * 128;

  for (int kt = 0; kt < 1024; kt += BK) {
#pragma unroll
    for (int i = 0; i < 2; i++) {
      int s = w * 128 + i * 64 + l;
      int row = s >> 2, c = (s & 3) * 8;
      const short* ga = Ab + (brow + row) * (size_t)1024 + kt + c;
      __builtin_amdgcn_global_load_lds(
          (const __attribute__((address_space(1))) unsigned int*)ga,
          (__attribute__((address_space(3))) unsigned int*)(As + (w * 128 + i * 64) * 8),
          16, 0, 0);
      const short* gb = Bb + (bcol + row) * (size_t)1024 + kt + c;
      __builtin_amdgcn_global_load_lds(
          (const __attribute__((address_space(1))) unsigned int*)gb,
          (__attribute__((address_space(3))) unsigned int*)(Bs + (w * 128 + i * 64) * 8),
          16, 0, 0);
    }
    __syncthreads();
    bf16x8 af[4], bfr[4];
#pragma unroll
    for (int mi = 0; mi < 4; mi++)
      af[mi] = *(const bf16x8*)(As + (wm * 64 + mi * 16 + (l & 15)) * BK + (l >> 4) * 8);
#pragma unroll
    for (int ni = 0; ni < 4; ni++)
      bfr[ni] = *(const bf16x8*)(Bs + (wn * 64 + ni * 16 + (l & 15)) * BK + (l >> 4) * 8);
#pragma unroll
    for (int mi = 0; mi < 4; mi++)
#pragma unroll
      for (int ni = 0; ni < 4; ni++)
        acc[mi][ni] = __builtin_amdgcn_mfma_f32_16x16x32_bf16(af[mi], bfr[ni], acc[mi][ni], 0, 0, 0);
    __syncthreads();
  }

  const int lr = (l >> 4) * 4, lc = l & 15;
#pragma unroll
  for (int mi = 0; mi < 4; mi++) {
#pragma unroll
    for (int ni = 0; ni < 4; ni++) {
      size_t gcol = bcol + wn * 64 + ni * 16 + lc;
      int half = split ? (gcol >= 1024) : 0;
      size_t cc = half ? (gcol - 1024) : gcol;
      const float* bp = half ? biasHi : biasLo;
      short* op = half ? Chi : Clo;
      float bvv = bp[cc];
#pragma unroll
      for (int r = 0; r < 4; r++) {
        size_t grow = brow + wm * 64 + mi * 16 + lr + r;
        op[grow * 1024 + cc] = f2b(acc[mi][ni][r] + bvv);
      }
    }
  }
}

// ========== merged u-GEMM + attention-softmax dispatch ==========
__global__ __launch_bounds__(256) void u_attn_kernel(const short* __restrict__ vbf,
                                                     const short* __restrict__ W1T,
                                                     short* __restrict__ ubuf,
                                                     const short* __restrict__ qbf,
                                                     const short* __restrict__ kbf,
                                                     float* __restrict__ p) {
  __shared__ short smem[8192];
  int bid = blockIdx.x;
  int t = threadIdx.x;
  if (bid < 2048) {
    constexpr int BK = 32;
    short* As = smem;
    short* Bs = smem + 4096;
    int h = bid >> 8;
    int L = bid & 255;
    int nb = (L & 7) * 32 + (L >> 3);
    int bn = nb & 15, bm = nb >> 4;
    const short* Ab = vbf + h * 128;
    const short* Bb = W1T + h * 128;
    short* Cb = ubuf + h * 2048;

    const int w = t >> 6, l = t & 63;
    const int wm = w >> 1, wn = w & 1;
    f32x4 acc[4][4] = {};
    const size_t brow = (size_t)bm * 128, bcol = (size_t)bn * 128;

    for (int kt = 0; kt < 128; kt += BK) {
#pragma unroll
      for (int i = 0; i < 2; i++) {
        int s = w * 128 + i * 64 + l;
        int row = s >> 2, c = (s & 3) * 8;
        const short* ga = Ab + (brow + row) * (size_t)1024 + kt + c;
        __builtin_amdgcn_global_load_lds(
            (const __attribute__((address_space(1))) unsigned int*)ga,
            (__attribute__((address_space(3))) unsigned int*)(As + (w * 128 + i * 64) * 8),
            16, 0, 0);
        const short* gb = Bb + (bcol + row) * (size_t)1024 + kt + c;
        __builtin_amdgcn_global_load_lds(
            (const __attribute__((address_space(1))) unsigned int*)gb,
            (__attribute__((address_space(3))) unsigned int*)(Bs + (w * 128 + i * 64) * 8),
            16, 0, 0);
      }
      __syncthreads();
      bf16x8 af[4], bfr[4];
#pragma unroll
      for (int mi = 0; mi < 4; mi++)
        af[mi] = *(const bf16x8*)(As + (wm * 64 + mi * 16 + (l & 15)) * BK + (l >> 4) * 8);
#pragma unroll
      for (int ni = 0; ni < 4; ni++)
        bfr[ni] = *(const bf16x8*)(Bs + (wn * 64 + ni * 16 + (l & 15)) * BK + (l >> 4) * 8);
#pragma unroll
      for (int mi = 0; mi < 4; mi++)
#pragma unroll
        for (int ni = 0; ni < 4; ni++)
          acc[mi][ni] = __builtin_amdgcn_mfma_f32_16x16x32_bf16(af[mi], bfr[ni], acc[mi][ni], 0, 0, 0);
      __syncthreads();
    }

    const int lr = (l >> 4) * 4, lc = l & 15;
#pragma unroll
    for (int mi = 0; mi < 4; mi++) {
#pragma unroll
      for (int ni = 0; ni < 4; ni++) {
        size_t gcol = bcol + wn * 64 + ni * 16 + lc;
#pragma unroll
        for (int r = 0; r < 4; r++) {
          size_t grow = brow + wm * 64 + mi * 16 + lr + r;
          Cb[grow * 16384 + gcol] = f2b(acc[mi][ni][r]);
        }
      }
    }
  } else {
    int blk = bid - 2048;  // b*32+sen
    int b = blk >> 5;
    float* qs = (float*)smem;
    float* ss = ((float*)smem) + 1024;
    {
      short4 qv = *(const short4*)(qbf + (size_t)blk * 1024 + t * 4);
      qs[t * 4 + 0] = b2f(qv.x);
      qs[t * 4 + 1] = b2f(qv.y);
      qs[t * 4 + 2] = b2f(qv.z);
      qs[t * 4 + 3] = b2f(qv.w);
    }
    __syncthreads();
    float sc[4];
#pragma unroll
    for (int i = 0; i < 4; i++) {
      int idx = i * 256 + t;
      int seg = idx >> 4, h = (idx >> 1) & 7, m = idx & 1;
      const short* kp = kbf + ((size_t)((b * 64 + seg) * 2 + m)) * 1024 + h * 128;
      float s = 0.f;
#pragma unroll
      for (int j = 0; j < 16; j++) {
        bf16x8 kv = *(const bf16x8*)(kp + j * 8);
#pragma unroll
        for (int e = 0; e < 8; e++) s += qs[h * 128 + j * 8 + e] * b2f(kv[e]);
      }
      sc[i] = s * 0.08838834764831845f;
    }
#pragma unroll
    for (int i = 0; i < 4; i++) ss[i * 256 + t] = sc[i];
    __syncthreads();
    for (int i = t; i < 512; i += 256) {
      float s0 = ss[2 * i], s1 = ss[2 * i + 1];
      float mx = fmaxf(s0, s1);
      float e0 = __expf(s0 - mx), e1 = __expf(s1 - mx);
      float inv = 1.f / (e0 + e1);
      int seg = i >> 3, h = i & 7;
      size_t base = (size_t)blk * 1024 + seg * 16;
      p[base + h] = e0 * inv;
      p[base + 8 + h] = e1 * inv;
    }
  }
}

// --------- 256x256 bf16 GEMM, BK=32, 64 KiB LDS -> 2 blocks/CU, trimmed barriers ----
// r9 schedule shape at half K-step: depth-2 prefetch, counted vmcnt(4), 3 barriers
// per K-tile. Swizzle for 64B rows: slot d ^= (row>>1)&3 (all 64 lane segments
// distinct; 2 rows per bank-group = free). Cross-block TLP (2 blocks/CU) overlaps
// one block's LDS/barrier phases with the other's MFMA clusters.
template <int RELU, int OUTBF, int BIAS>
__global__ __launch_bounds__(512, 4) void gemm256(const short* __restrict__ Abf, int lda,
                                                  const short* __restrict__ Btbf, int ldb,
                                                  const float* __restrict__ bias,
                                                  void* __restrict__ Cout, int ldc, int K) {
  __shared__ __align__(16) short As[2][256 * 32];
  __shared__ __align__(16) short Bs[2][256 * 32];
  const int t = threadIdx.x;
  const int w = t >> 6, l = t & 63;
  const int wr = w >> 2, wc = w & 3;       // 2 x 4 wave grid
  const int l15 = l & 15, lhi = l >> 4;

  int nwg = gridDim.x * gridDim.y;
  int L = blockIdx.y * gridDim.x + blockIdx.x;
  int bm, bn;
  if ((nwg & 7) == 0) {
    int cpx = nwg >> 3;
    int nb = (L & 7) * cpx + (L >> 3);
    bn = nb % gridDim.x;
    bm = nb / gridDim.x;
  } else {
    bn = blockIdx.x;
    bm = blockIdx.y;
  }
  const size_t brow = (size_t)bm * 256, bcol = (size_t)bn * 256;
  const int NT = K >> 5;

  // Stage one 256x32 operand tile: 1024 16B segments, 2 loads/thread.
  // Global source pre-swizzled so linear LDS + swizzled read = identity.
  auto stage = [&](short* dst, const short* src, int ld, size_t rowoff, int kt) {
#pragma unroll
    for (int i = 0; i < 2; ++i) {
      int seg = i * 512 + t;
      int row = seg >> 2, s = seg & 3;
      int sw = s ^ ((row >> 1) & 3);
      const short* g = src + (rowoff + row) * (size_t)ld + kt + (sw << 3);
      __builtin_amdgcn_global_load_lds(
          (const __attribute__((address_space(1))) unsigned int*)g,
          (__attribute__((address_space(3))) unsigned int*)(dst + seg * 8),
          16, 0, 0);
    }
  };
  auto rdA = [&](const short* base, int m) -> bf16x8 {
    int r = wr * 128 + m * 16 + l15;
    int d = lhi ^ ((r >> 1) & 3);
    return *(const bf16x8*)(base + (r << 5) + (d << 3));
  };
  auto rdB = [&](const short* base, int n) -> bf16x8 {
    int r = wc * 64 + n * 16 + l15;
    int d = lhi ^ ((r >> 1) & 3);
    return *(const bf16x8*)(base + (r << 5) + (d << 3));
  };

  f32x4 acc[8][4] = {};
  bf16x8 afr[4], af2[4], bfr[4];

  // Prologue: stage K-tiles 0 and 1; certify tile 0 (counted vmcnt).
  stage(Bs[0], Btbf, ldb, bcol, 0);
  stage(As[0], Abf, lda, brow, 0);
  stage(Bs[1], Btbf, ldb, bcol, 32);
  stage(As[1], Abf, lda, brow, 32);
  asm volatile("s_waitcnt vmcnt(4)" ::: "memory");
  BAR;

  for (int T = 0; T < NT; ++T) {
    const short* Ab = As[T & 1];
    const short* Bb = Bs[T & 1];
    short* Aw = (short*)As[T & 1];   // T+2 shares parity with T
    short* Bw = (short*)Bs[T & 1];
    const int ktn = (T + 2) * 32;
    const bool st = (T + 2) < NT;

    // ---- P0: read A m0-3 + B n0-3 ; MFMA m0-3 x n0-3 ----
#pragma unroll
    for (int m = 0; m < 4; ++m) afr[m] = rdA(Ab, m);
#pragma unroll
    for (int n = 0; n < 4; ++n) bfr[n] = rdB(Bb, n);
    __builtin_amdgcn_s_setprio(1);
#pragma unroll
    for (int m = 0; m < 4; ++m)
#pragma unroll
      for (int n = 0; n < 4; ++n)
        acc[m][n] = __builtin_amdgcn_mfma_f32_16x16x32_bf16(afr[m], bfr[n], acc[m][n], 0, 0, 0);
    __builtin_amdgcn_s_setprio(0);
    BAR;  // all B reads drained (P0 MFMA waited) -> B overwrite safe

    // ---- P1: stage B(T+2) ; read A m4-7 ; MFMA m4-7 x n0-1 ----
    if (st) stage(Bw, Btbf, ldb, bcol, ktn);
#pragma unroll
    for (int m = 0; m < 4; ++m) af2[m] = rdA(Ab, m + 4);
    __builtin_amdgcn_s_setprio(1);
#pragma unroll
    for (int m = 0; m < 4; ++m)
#pragma unroll
      for (int n = 0; n < 2; ++n)
        acc[m + 4][n] = __builtin_amdgcn_mfma_f32_16x16x32_bf16(af2[m], bfr[n], acc[m + 4][n], 0, 0, 0);
    __builtin_amdgcn_s_setprio(0);
    BAR;  // all A reads drained -> A overwrite safe

    // ---- P2: stage A(T+2) ; MFMA m4-7 x n2-3 ; counted vmcnt certifies T+1 ----
    if (st) stage(Aw, Abf, lda, brow, ktn);
    __builtin_amdgcn_s_setprio(1);
#pragma unroll
    for (int m = 0; m < 4; ++m)
#pragma unroll
      for (int n = 2; n < 4; ++n)
        acc[m + 4][n] = __builtin_amdgcn_mfma_f32_16x16x32_bf16(af2[m], bfr[n], acc[m + 4][n], 0, 0, 0);
    __builtin_amdgcn_s_setprio(0);
    if (st) { asm volatile("s_waitcnt vmcnt(4)" ::: "memory"); }
    else    { asm volatile("s_waitcnt vmcnt(0)" ::: "memory"); }
    BAR;  // T+1 data certified for next-tile reads
  }

  // ---- Epilogue ----
#pragma unroll
  for (int m = 0; m < 8; ++m) {
#pragma unroll
    for (int n = 0; n < 4; ++n) {
      size_t col = bcol + wc * 64 + n * 16 + l15;
      float bvv = BIAS ? bias[col] : 0.f;
#pragma unroll
      for (int r = 0; r < 4; ++r) {
        size_t row = brow + wr * 128 + m * 16 + lhi * 4 + r;
        float val = acc[m][n][r] + bvv;
        if (RELU) val = fmaxf(val, 0.f);
        if (OUTBF)
          ((short*)Cout)[row * (size_t)ldc + col] = f2b(val);
        else
          ((float*)Cout)[row * (size_t)ldc + col] = val;
      }
    }
  }
}

// ---------------- mix: H[row,f] = relu(sum_{m,h} p*u + b1) ----------------
__global__ __launch_bounds__(512) void mix_kernel(const short* __restrict__ u,
                                                  const float* __restrict__ p,
                                                  const float* __restrict__ b1,
                                                  short* __restrict__ H) {
  int blk = blockIdx.x;  // b*64+seg
  int b = blk >> 6, seg = blk & 63;
  int t = threadIdx.x;
  __shared__ float ps[512];
  {
    int sen = t >> 4, j = t & 15;
    ps[t] = p[(size_t)(b * 32 + sen) * 1024 + seg * 16 + j];
  }
  int f0 = t * 4;
  float ur[16][4];
#pragma unroll
  for (int mh = 0; mh < 16; ++mh) {
    int m = mh >> 3, h = mh & 7;
    const short* up = u + ((size_t)(blk * 2 + m)) * 16384 + h * 2048 + f0;
    short4 uv = *(const short4*)up;
    ur[mh][0] = b2f(uv.x); ur[mh][1] = b2f(uv.y);
    ur[mh][2] = b2f(uv.z); ur[mh][3] = b2f(uv.w);
  }
  float4 bb = *(const float4*)(b1 + f0);
  __syncthreads();
  for (int sen = 0; sen < 32; ++sen) {
    float a0 = bb.x, a1 = bb.y, a2 = bb.z, a3 = bb.w;
#pragma unroll
    for (int mh = 0; mh < 16; ++mh) {
      float wv = ps[sen * 16 + mh];
      a0 += wv * ur[mh][0];
      a1 += wv * ur[mh][1];
      a2 += wv * ur[mh][2];
      a3 += wv * ur[mh][3];
    }
    short4 o;
    o.x = f2b(fmaxf(a0, 0.f));
    o.y = f2b(fmaxf(a1, 0.f));
    o.z = f2b(fmaxf(a2, 0.f));
    o.w = f2b(fmaxf(a3, 0.f));
    size_t row = (size_t)(b * 32 + sen) * 64 + seg;
    *(short4*)(H + row * 2048 + f0) = o;
  }
}

extern "C" void kernel_launch(void* const* d_in, const int* in_sizes, int n_in,
                              void* d_out, int out_size, void* d_ws, size_t ws_size,
                              hipStream_t stream) {
  const float* A = (const float*)d_in[0];
  const float* V = (const float*)d_in[1];
  const float* S = (const float*)d_in[2];
  const float* Wq = (const float*)d_in[3];
  const float* bq = (const float*)d_in[4];
  const float* Wk = (const float*)d_in[5];
  const float* bk = (const float*)d_in[6];
  const float* Wv = (const float*)d_in[7];
  const float* bv = (const float*)d_in[8];
  const float* gamma = (const float*)d_in[9];
  const float* beta = (const float*)d_in[10];
  const float* W1 = (const float*)d_in[11];
  const float* b1 = (const float*)d_in[12];
  const float* W2 = (const float*)d_in[13];
  const float* b2 = (const float*)d_in[14];

  const size_t MiB = 1048576;
  char* ws = (char*)d_ws;
  short* avbf = (short*)(ws + 0 * MiB);    // 2048x1024 bf16 (4 MiB)
  short* WkT  = (short*)(ws + 4 * MiB);    // 1024x1024     (2 MiB)  } adjacent: merged KV B
  short* WvT  = (short*)(ws + 6 * MiB);    // 1024x1024     (2 MiB)  }
  short* WqT  = (short*)(ws + 8 * MiB);    // 1024x1024     (2 MiB)
  short* W1T  = (short*)(ws + 10 * MiB);   // 2048x1024     (4 MiB)
  short* W2T  = (short*)(ws + 14 * MiB);   // 1024x2048     (4 MiB)
  short* Snbf = (short*)(ws + 18 * MiB);   // 512x1024      (1 MiB)
  short* kbf  = (short*)(ws + 19 * MiB);   // 2048x1024     (4 MiB)
  short* vbf  = (short*)(ws + 23 * MiB);   // 2048x1024     (4 MiB)
  short* qbf  = (short*)(ws + 27 * MiB);   // 512x1024      (1 MiB)
  float* pbuf = (float*)(ws + 28 * MiB);   // 32768x16 f32  (2 MiB)
  short* ubuf = (short*)(ws + 30 * MiB);   // 2048x8x2048   (64 MiB)
  short* Hbf  = (short*)(ws + 94 * MiB);   // 32768x2048    (128 MiB)

  // 1. fused prep: build_av + 5 transposes + LN
  prep_kernel<<<9728, 256, 0, stream>>>(A, V, avbf, Wk, WkT, Wv, WvT, Wq, WqT,
                                        W1, W1T, W2, W2T, S, gamma, beta, Snbf);

  // 2. fused K+V (split) + Q projections
  gemm_kvq<<<288, 256, 0, stream>>>(avbf, WkT, bk, bv, kbf, vbf, Snbf, WqT, bq, qbf);

  // 3. merged: u-GEMM (2048 blocks) + attention softmax (512 blocks)
  u_attn_kernel<<<2560, 256, 0, stream>>>(vbf, W1T, ubuf, qbf, kbf, pbuf);

  // 4. H = relu(sum p*u + b1)
  mix_kernel<<<1024, 512, 0, stream>>>(ubuf, pbuf, b1, Hbf);

  // 5. FFN2: out = H @ W2 + b2 (fp32 out) — 256^2, BK=32, 2 blocks/CU
  gemm256<0, 0, 1><<<dim3(4, 128), 512, 0, stream>>>(Hbf, 2048, W2T, 2048, b2,
                                                     (float*)d_out, 1024, 2048);
}

// Round 11
// 311.293 us; speedup vs baseline: 4.2833x; 4.2833x over previous
//
#include <hip/hip_runtime.h>
#include <hip/hip_bf16.h>

// Shapes
#define BSZ 16
#define NSEG 64
#define NSEN 32
#define DM 1024
#define NH 8
#define DKH 128
#define DFF 2048

typedef short bf16x8 __attribute__((ext_vector_type(8)));
typedef float f32x4 __attribute__((ext_vector_type(4)));

__device__ __forceinline__ float b2f(short u) {
  union { unsigned int i; float f; } c;
  c.i = ((unsigned int)(unsigned short)u) << 16;
  return c.f;
}
__device__ __forceinline__ short f2b(float f) {
  __hip_bfloat16 h = __float2bfloat16(f);
  return *reinterpret_cast<short*>(&h);
}

#define SCHED0 __builtin_amdgcn_sched_barrier(0)
#define BAR do { SCHED0; __builtin_amdgcn_s_barrier(); SCHED0; } while (0)

// ================= fused prep: build_av + 5 weight transposes + LN =================
__device__ __forceinline__ void transpose_body(const float* __restrict__ W,
                                               short* __restrict__ Wt,
                                               int K, int N, int bx, int by,
                                               float* tile /*32*33*/) {
  int tx = threadIdx.x & 31, ty = threadIdx.x >> 5;
  int n0 = bx * 32, k0 = by * 32;
#pragma unroll
  for (int i = 0; i < 32; i += 8)
    tile[(ty + i) * 33 + tx] = W[(size_t)(k0 + ty + i) * N + n0 + tx];
  __syncthreads();
#pragma unroll
  for (int i = 0; i < 32; i += 8)
    Wt[(size_t)(n0 + ty + i) * K + k0 + tx] = f2b(tile[tx * 33 + ty + i]);
}

__global__ __launch_bounds__(256) void prep_kernel(
    const float* __restrict__ A, const float* __restrict__ V, short* __restrict__ avbf,
    const float* __restrict__ Wk, short* __restrict__ WkT,
    const float* __restrict__ Wv, short* __restrict__ WvT,
    const float* __restrict__ Wq, short* __restrict__ WqT,
    const float* __restrict__ W1, short* __restrict__ W1T,
    const float* __restrict__ W2, short* __restrict__ W2T,
    const float* __restrict__ S, const float* __restrict__ gamma,
    const float* __restrict__ beta, short* __restrict__ Snbf) {
  __shared__ float smem[32 * 33];
  int bid = blockIdx.x;
  int t = threadIdx.x;
  if (bid < 2048) {
    int i = bid * 256 + t;
    size_t o = (size_t)i * 4;
    int r = (int)(o >> 10);
    int d = (int)(o & 1023);
    int m = r & 1;
    int bseg = r >> 1;
    const float* src = (m ? V : A) + (size_t)bseg * 1024 + d;
    float4 v = *(const float4*)src;
    short4 out;
    out.x = f2b(v.x); out.y = f2b(v.y); out.z = f2b(v.z); out.w = f2b(v.w);
    *(short4*)(avbf + o) = out;
  } else if (bid < 3072) {
    int id = bid - 2048;
    transpose_body(Wk, WkT, 1024, 1024, id & 31, id >> 5, smem);
  } else if (bid < 4096) {
    int id = bid - 3072;
    transpose_body(Wv, WvT, 1024, 1024, id & 31, id >> 5, smem);
  } else if (bid < 5120) {
    int id = bid - 4096;
    transpose_body(Wq, WqT, 1024, 1024, id & 31, id >> 5, smem);
  } else if (bid < 7168) {
    int id = bid - 5120;
    transpose_body(W1, W1T, 1024, 2048, id & 63, id >> 6, smem);
  } else if (bid < 9216) {
    int id = bid - 7168;
    transpose_body(W2, W2T, 2048, 1024, id & 31, id >> 5, smem);
  } else {
    int row = bid - 9216;
    int l = t & 63, w = t >> 6;
    const float* x = S + (size_t)row * 1024;
    float4 v = ((const float4*)x)[t];
    float s = v.x + v.y + v.z + v.w;
#pragma unroll
    for (int off = 32; off; off >>= 1) s += __shfl_down(s, off);
    if (l == 0) smem[w] = s;
    __syncthreads();
    if (t == 0) smem[4] = (smem[0] + smem[1] + smem[2] + smem[3]) * (1.0f / 1024.0f);
    __syncthreads();
    float mean = smem[4];
    float4 c = {v.x - mean, v.y - mean, v.z - mean, v.w - mean};
    float s2 = c.x * c.x + c.y * c.y + c.z * c.z + c.w * c.w;
#pragma unroll
    for (int off = 32; off; off >>= 1) s2 += __shfl_down(s2, off);
    __syncthreads();
    if (l == 0) smem[w] = s2;
    __syncthreads();
    if (t == 0) smem[5] = (smem[0] + smem[1] + smem[2] + smem[3]) * (1.0f / 1024.0f);
    __syncthreads();
    float rstd = rsqrtf(smem[5] + 1e-5f);
    int base = t * 4;
    short4 o;
    o.x = f2b(c.x * rstd * gamma[base + 0] + beta[base + 0]);
    o.y = f2b(c.y * rstd * gamma[base + 1] + beta[base + 1]);
    o.z = f2b(c.z * rstd * gamma[base + 2] + beta[base + 2]);
    o.w = f2b(c.w * rstd * gamma[base + 3] + beta[base + 3]);
    *(short4*)(Snbf + (size_t)row * 1024 + base) = o;
  }
}

// ================ fused KV + Q projections (m97 128x128 body, K=1024) ================
__global__ __launch_bounds__(256) void gemm_kvq(const short* __restrict__ avbf,
                                                const short* __restrict__ WkvT,
                                                const float* __restrict__ bk,
                                                const float* __restrict__ bv,
                                                short* __restrict__ kbf,
                                                short* __restrict__ vbf,
                                                const short* __restrict__ Snbf,
                                                const short* __restrict__ WqT,
                                                const float* __restrict__ bq,
                                                short* __restrict__ qbf) {
  constexpr int BK = 32;
  __shared__ short As[128 * BK];
  __shared__ short Bs[128 * BK];
  int bid = blockIdx.x;
  const short *Ab, *Bb;
  const float *biasLo, *biasHi;
  short *Clo, *Chi;
  int bm, bn;
  bool split;
  if (bid < 256) {
    int nb = (bid & 7) * 32 + (bid >> 3);
    bn = nb & 15; bm = nb >> 4;
    Ab = avbf; Bb = WkvT; biasLo = bk; biasHi = bv; Clo = kbf; Chi = vbf; split = true;
  } else {
    int id = bid - 256;
    bm = id >> 3; bn = id & 7;
    Ab = Snbf; Bb = WqT; biasLo = bq; biasHi = bq; Clo = qbf; Chi = qbf; split = false;
  }

  const int t = threadIdx.x, w = t >> 6, l = t & 63;
  const int wm = w >> 1, wn = w & 1;
  f32x4 acc[4][4] = {};
  const size_t brow = (size_t)bm * 128, bcol = (size_t)bn * 128;

  for (int kt = 0; kt < 1024; kt += BK) {
#pragma unroll
    for (int i = 0; i < 2; i++) {
      int s = w * 128 + i * 64 + l;
      int row = s >> 2, c = (s & 3) * 8;
      const short* ga = Ab + (brow + row) * (size_t)1024 + kt + c;
      __builtin_amdgcn_global_load_lds(
          (const __attribute__((address_space(1))) unsigned int*)ga,
          (__attribute__((address_space(3))) unsigned int*)(As + (w * 128 + i * 64) * 8),
          16, 0, 0);
      const short* gb = Bb + (bcol + row) * (size_t)1024 + kt + c;
      __builtin_amdgcn_global_load_lds(
          (const __attribute__((address_space(1))) unsigned int*)gb,
          (__attribute__((address_space(3))) unsigned int*)(Bs + (w * 128 + i * 64) * 8),
          16, 0, 0);
    }
    __syncthreads();
    bf16x8 af[4], bfr[4];
#pragma unroll
    for (int mi = 0; mi < 4; mi++)
      af[mi] = *(const bf16x8*)(As + (wm * 64 + mi * 16 + (l & 15)) * BK + (l >> 4) * 8);
#pragma unroll
    for (int ni = 0; ni < 4; ni++)
      bfr[ni] = *(const bf16x8*)(Bs + (wn * 64 + ni * 16 + (l & 15)) * BK + (l >> 4) * 8);
#pragma unroll
    for (int mi = 0; mi < 4; mi++)
#pragma unroll
      for (int ni = 0; ni < 4; ni++)
        acc[mi][ni] = __builtin_amdgcn_mfma_f32_16x16x32_bf16(af[mi], bfr[ni], acc[mi][ni], 0, 0, 0);
    __syncthreads();
  }

  const int lr = (l >> 4) * 4, lc = l & 15;
#pragma unroll
  for (int mi = 0; mi < 4; mi++) {
#pragma unroll
    for (int ni = 0; ni < 4; ni++) {
      size_t gcol = bcol + wn * 64 + ni * 16 + lc;
      int half = split ? (gcol >= 1024) : 0;
      size_t cc = half ? (gcol - 1024) : gcol;
      const float* bp = half ? biasHi : biasLo;
      short* op = half ? Chi : Clo;
      float bvv = bp[cc];
#pragma unroll
      for (int r = 0; r < 4; r++) {
        size_t grow = brow + wm * 64 + mi * 16 + lr + r;
        op[grow * 1024 + cc] = f2b(acc[mi][ni][r] + bvv);
      }
    }
  }
}

// ========== merged u-GEMM + attention-softmax dispatch ==========
__global__ __launch_bounds__(256) void u_attn_kernel(const short* __restrict__ vbf,
                                                     const short* __restrict__ W1T,
                                                     short* __restrict__ ubuf,
                                                     const short* __restrict__ qbf,
                                                     const short* __restrict__ kbf,
                                                     float* __restrict__ p) {
  __shared__ short smem[8192];
  int bid = blockIdx.x;
  int t = threadIdx.x;
  if (bid < 2048) {
    constexpr int BK = 32;
    short* As = smem;
    short* Bs = smem + 4096;
    int h = bid >> 8;
    int L = bid & 255;
    int nb = (L & 7) * 32 + (L >> 3);
    int bn = nb & 15, bm = nb >> 4;
    const short* Ab = vbf + h * 128;
    const short* Bb = W1T + h * 128;
    short* Cb = ubuf + h * 2048;

    const int w = t >> 6, l = t & 63;
    const int wm = w >> 1, wn = w & 1;
    f32x4 acc[4][4] = {};
    const size_t brow = (size_t)bm * 128, bcol = (size_t)bn * 128;

    for (int kt = 0; kt < 128; kt += BK) {
#pragma unroll
      for (int i = 0; i < 2; i++) {
        int s = w * 128 + i * 64 + l;
        int row = s >> 2, c = (s & 3) * 8;
        const short* ga = Ab + (brow + row) * (size_t)1024 + kt + c;
        __builtin_amdgcn_global_load_lds(
            (const __attribute__((address_space(1))) unsigned int*)ga,
            (__attribute__((address_space(3))) unsigned int*)(As + (w * 128 + i * 64) * 8),
            16, 0, 0);
        const short* gb = Bb + (bcol + row) * (size_t)1024 + kt + c;
        __builtin_amdgcn_global_load_lds(
            (const __attribute__((address_space(1))) unsigned int*)gb,
            (__attribute__((address_space(3))) unsigned int*)(Bs + (w * 128 + i * 64) * 8),
            16, 0, 0);
      }
      __syncthreads();
      bf16x8 af[4], bfr[4];
#pragma unroll
      for (int mi = 0; mi < 4; mi++)
        af[mi] = *(const bf16x8*)(As + (wm * 64 + mi * 16 + (l & 15)) * BK + (l >> 4) * 8);
#pragma unroll
      for (int ni = 0; ni < 4; ni++)
        bfr[ni] = *(const bf16x8*)(Bs + (wn * 64 + ni * 16 + (l & 15)) * BK + (l >> 4) * 8);
#pragma unroll
      for (int mi = 0; mi < 4; mi++)
#pragma unroll
        for (int ni = 0; ni < 4; ni++)
          acc[mi][ni] = __builtin_amdgcn_mfma_f32_16x16x32_bf16(af[mi], bfr[ni], acc[mi][ni], 0, 0, 0);
      __syncthreads();
    }

    const int lr = (l >> 4) * 4, lc = l & 15;
#pragma unroll
    for (int mi = 0; mi < 4; mi++) {
#pragma unroll
      for (int ni = 0; ni < 4; ni++) {
        size_t gcol = bcol + wn * 64 + ni * 16 + lc;
#pragma unroll
        for (int r = 0; r < 4; r++) {
          size_t grow = brow + wm * 64 + mi * 16 + lr + r;
          Cb[grow * 16384 + gcol] = f2b(acc[mi][ni][r]);
        }
      }
    }
  } else {
    int blk = bid - 2048;  // b*32+sen
    int b = blk >> 5;
    float* qs = (float*)smem;
    float* ss = ((float*)smem) + 1024;
    {
      short4 qv = *(const short4*)(qbf + (size_t)blk * 1024 + t * 4);
      qs[t * 4 + 0] = b2f(qv.x);
      qs[t * 4 + 1] = b2f(qv.y);
      qs[t * 4 + 2] = b2f(qv.z);
      qs[t * 4 + 3] = b2f(qv.w);
    }
    __syncthreads();
    float sc[4];
#pragma unroll
    for (int i = 0; i < 4; i++) {
      int idx = i * 256 + t;
      int seg = idx >> 4, h = (idx >> 1) & 7, m = idx & 1;
      const short* kp = kbf + ((size_t)((b * 64 + seg) * 2 + m)) * 1024 + h * 128;
      float s = 0.f;
#pragma unroll
      for (int j = 0; j < 16; j++) {
        bf16x8 kv = *(const bf16x8*)(kp + j * 8);
#pragma unroll
        for (int e = 0; e < 8; e++) s += qs[h * 128 + j * 8 + e] * b2f(kv[e]);
      }
      sc[i] = s * 0.08838834764831845f;
    }
#pragma unroll
    for (int i = 0; i < 4; i++) ss[i * 256 + t] = sc[i];
    __syncthreads();
    for (int i = t; i < 512; i += 256) {
      float s0 = ss[2 * i], s1 = ss[2 * i + 1];
      float mx = fmaxf(s0, s1);
      float e0 = __expf(s0 - mx), e1 = __expf(s1 - mx);
      float inv = 1.f / (e0 + e1);
      int seg = i >> 3, h = i & 7;
      size_t base = (size_t)blk * 1024 + seg * 16;
      p[base + h] = e0 * inv;
      p[base + 8 + h] = e1 * inv;
    }
  }
}

// ------ 256x128 bf16 GEMM, BK=32, 48 KiB LDS, acc=64 VGPR -> 2 blocks/CU ----------
// r9 trimmed-barrier schedule (3/tile), depth-2 prefetch, counted vmcnt(3).
// 8 waves as 2x4; per-wave output 128x32 -> acc[8][2] (64 VGPRs, fits 16 waves/CU).
// Swizzle for 64B rows: slot d ^= (row>>1)&3 -> uniform 8 lanes/slot (conflict-free).
template <int RELU, int OUTBF, int BIAS>
__global__ __launch_bounds__(512, 4) void gemm256(const short* __restrict__ Abf, int lda,
                                                  const short* __restrict__ Btbf, int ldb,
                                                  const float* __restrict__ bias,
                                                  void* __restrict__ Cout, int ldc, int K) {
  __shared__ __align__(16) short As[2][256 * 32];
  __shared__ __align__(16) short Bs[2][128 * 32];
  const int t = threadIdx.x;
  const int w = t >> 6, l = t & 63;
  const int wr = w >> 2, wc = w & 3;       // 2 x 4 wave grid: 128 rows x 32 cols each
  const int l15 = l & 15, lhi = l >> 4;

  int nwg = gridDim.x * gridDim.y;
  int L = blockIdx.y * gridDim.x + blockIdx.x;
  int bm, bn;
  if ((nwg & 7) == 0) {
    int cpx = nwg >> 3;
    int nb = (L & 7) * cpx + (L >> 3);
    bn = nb % gridDim.x;
    bm = nb / gridDim.x;
  } else {
    bn = blockIdx.x;
    bm = blockIdx.y;
  }
  const size_t brow = (size_t)bm * 256, bcol = (size_t)bn * 128;
  const int NT = K >> 5;

  // A tile: 256x32 = 1024 segs (2 loads/thread). B tile: 128x32 = 512 segs (1 load).
  // Global source pre-swizzled so linear LDS dest + swizzled read = identity.
  auto stageA = [&](short* dst, const short* src, int ld, int kt) {
#pragma unroll
    for (int i = 0; i < 2; ++i) {
      int seg = i * 512 + t;
      int row = seg >> 2, s = seg & 3;
      int sw = s ^ ((row >> 1) & 3);
      const short* g = src + (brow + row) * (size_t)ld + kt + (sw << 3);
      __builtin_amdgcn_global_load_lds(
          (const __attribute__((address_space(1))) unsigned int*)g,
          (__attribute__((address_space(3))) unsigned int*)(dst + seg * 8),
          16, 0, 0);
    }
  };
  auto stageB = [&](short* dst, const short* src, int ld, int kt) {
    int row = t >> 2, s = t & 3;
    int sw = s ^ ((row >> 1) & 3);
    const short* g = src + (bcol + row) * (size_t)ld + kt + (sw << 3);
    __builtin_amdgcn_global_load_lds(
        (const __attribute__((address_space(1))) unsigned int*)g,
        (__attribute__((address_space(3))) unsigned int*)(dst + t * 8),
        16, 0, 0);
  };
  auto rdA = [&](const short* base, int m) -> bf16x8 {
    int r = wr * 128 + m * 16 + l15;
    int d = lhi ^ ((r >> 1) & 3);
    return *(const bf16x8*)(base + (r << 5) + (d << 3));
  };
  auto rdB = [&](const short* base, int n) -> bf16x8 {
    int r = wc * 32 + n * 16 + l15;
    int d = lhi ^ ((r >> 1) & 3);
    return *(const bf16x8*)(base + (r << 5) + (d << 3));
  };

  f32x4 acc[8][2] = {};
  bf16x8 afr[4], af2[4], bfr[2];

  // Prologue: stage tiles 0,1 (3 loads each); certify tile 0 via counted vmcnt.
  stageB(Bs[0], Btbf, ldb, 0);
  stageA(As[0], Abf, lda, 0);
  stageB(Bs[1], Btbf, ldb, 32);
  stageA(As[1], Abf, lda, 32);
  asm volatile("s_waitcnt vmcnt(3)" ::: "memory");
  BAR;

  for (int T = 0; T < NT; ++T) {
    const short* Ab = As[T & 1];
    const short* Bb = Bs[T & 1];
    short* Aw = (short*)As[T & 1];   // T+2 shares parity with T
    short* Bw = (short*)Bs[T & 1];
    const int ktn = (T + 2) * 32;
    const bool st = (T + 2) < NT;

    // ---- P0: read A m0-3 + B n0-1 ; MFMA m0-3 x n0-1 ----
#pragma unroll
    for (int m = 0; m < 4; ++m) afr[m] = rdA(Ab, m);
#pragma unroll
    for (int n = 0; n < 2; ++n) bfr[n] = rdB(Bb, n);
    __builtin_amdgcn_s_setprio(1);
#pragma unroll
    for (int m = 0; m < 4; ++m)
#pragma unroll
      for (int n = 0; n < 2; ++n)
        acc[m][n] = __builtin_amdgcn_mfma_f32_16x16x32_bf16(afr[m], bfr[n], acc[m][n], 0, 0, 0);
    __builtin_amdgcn_s_setprio(0);
    BAR;  // B reads drained (P0 MFMA waited on them) -> B overwrite safe

    // ---- P1: stage B(T+2) ; read A m4-7 ; MFMA m4-7 x n0-1 ----
    if (st) stageB(Bw, Btbf, ldb, ktn);
#pragma unroll
    for (int m = 0; m < 4; ++m) af2[m] = rdA(Ab, m + 4);
    __builtin_amdgcn_s_setprio(1);
#pragma unroll
    for (int m = 0; m < 4; ++m)
#pragma unroll
      for (int n = 0; n < 2; ++n)
        acc[m + 4][n] = __builtin_amdgcn_mfma_f32_16x16x32_bf16(af2[m], bfr[n], acc[m + 4][n], 0, 0, 0);
    __builtin_amdgcn_s_setprio(0);
    BAR;  // all A reads drained -> A overwrite safe

    // ---- P2: stage A(T+2) ; counted vmcnt certifies T+1 ----
    if (st) { stageA(Aw, Abf, lda, ktn);
              asm volatile("s_waitcnt vmcnt(3)" ::: "memory"); }
    else    { asm volatile("s_waitcnt vmcnt(0)" ::: "memory"); }
    BAR;  // T+1 data certified for next-tile reads
  }

  // ---- Epilogue: per wave 128 rows x 32 cols ----
#pragma unroll
  for (int m = 0; m < 8; ++m) {
#pragma unroll
    for (int n = 0; n < 2; ++n) {
      size_t col = bcol + wc * 32 + n * 16 + l15;
      float bvv = BIAS ? bias[col] : 0.f;
#pragma unroll
      for (int r = 0; r < 4; ++r) {
        size_t row = brow + wr * 128 + m * 16 + lhi * 4 + r;
        float val = acc[m][n][r] + bvv;
        if (RELU) val = fmaxf(val, 0.f);
        if (OUTBF)
          ((short*)Cout)[row * (size_t)ldc + col] = f2b(val);
        else
          ((float*)Cout)[row * (size_t)ldc + col] = val;
      }
    }
  }
}

// ---------------- mix: H[row,f] = relu(sum_{m,h} p*u + b1) ----------------
__global__ __launch_bounds__(512) void mix_kernel(const short* __restrict__ u,
                                                  const float* __restrict__ p,
                                                  const float* __restrict__ b1,
                                                  short* __restrict__ H) {
  int blk = blockIdx.x;  // b*64+seg
  int b = blk >> 6, seg = blk & 63;
  int t = threadIdx.x;
  __shared__ float ps[512];
  {
    int sen = t >> 4, j = t & 15;
    ps[t] = p[(size_t)(b * 32 + sen) * 1024 + seg * 16 + j];
  }
  int f0 = t * 4;
  float ur[16][4];
#pragma unroll
  for (int mh = 0; mh < 16; ++mh) {
    int m = mh >> 3, h = mh & 7;
    const short* up = u + ((size_t)(blk * 2 + m)) * 16384 + h * 2048 + f0;
    short4 uv = *(const short4*)up;
    ur[mh][0] = b2f(uv.x); ur[mh][1] = b2f(uv.y);
    ur[mh][2] = b2f(uv.z); ur[mh][3] = b2f(uv.w);
  }
  float4 bb = *(const float4*)(b1 + f0);
  __syncthreads();
  for (int sen = 0; sen < 32; ++sen) {
    float a0 = bb.x, a1 = bb.y, a2 = bb.z, a3 = bb.w;
#pragma unroll
    for (int mh = 0; mh < 16; ++mh) {
      float wv = ps[sen * 16 + mh];
      a0 += wv * ur[mh][0];
      a1 += wv * ur[mh][1];
      a2 += wv * ur[mh][2];
      a3 += wv * ur[mh][3];
    }
    short4 o;
    o.x = f2b(fmaxf(a0, 0.f));
    o.y = f2b(fmaxf(a1, 0.f));
    o.z = f2b(fmaxf(a2, 0.f));
    o.w = f2b(fmaxf(a3, 0.f));
    size_t row = (size_t)(b * 32 + sen) * 64 + seg;
    *(short4*)(H + row * 2048 + f0) = o;
  }
}

extern "C" void kernel_launch(void* const* d_in, const int* in_sizes, int n_in,
                              void* d_out, int out_size, void* d_ws, size_t ws_size,
                              hipStream_t stream) {
  const float* A = (const float*)d_in[0];
  const float* V = (const float*)d_in[1];
  const float* S = (const float*)d_in[2];
  const float* Wq = (const float*)d_in[3];
  const float* bq = (const float*)d_in[4];
  const float* Wk = (const float*)d_in[5];
  const float* bk = (const float*)d_in[6];
  const float* Wv = (const float*)d_in[7];
  const float* bv = (const float*)d_in[8];
  const float* gamma = (const float*)d_in[9];
  const float* beta = (const float*)d_in[10];
  const float* W1 = (const float*)d_in[11];
  const float* b1 = (const float*)d_in[12];
  const float* W2 = (const float*)d_in[13];
  const float* b2 = (const float*)d_in[14];

  const size_t MiB = 1048576;
  char* ws = (char*)d_ws;
  short* avbf = (short*)(ws + 0 * MiB);    // 2048x1024 bf16 (4 MiB)
  short* WkT  = (short*)(ws + 4 * MiB);    // 1024x1024     (2 MiB)  } adjacent: merged KV B
  short* WvT  = (short*)(ws + 6 * MiB);    // 1024x1024     (2 MiB)  }
  short* WqT  = (short*)(ws + 8 * MiB);    // 1024x1024     (2 MiB)
  short* W1T  = (short*)(ws + 10 * MiB);   // 2048x1024     (4 MiB)
  short* W2T  = (short*)(ws + 14 * MiB);   // 1024x2048     (4 MiB)
  short* Snbf = (short*)(ws + 18 * MiB);   // 512x1024      (1 MiB)
  short* kbf  = (short*)(ws + 19 * MiB);   // 2048x1024     (4 MiB)
  short* vbf  = (short*)(ws + 23 * MiB);   // 2048x1024     (4 MiB)
  short* qbf  = (short*)(ws + 27 * MiB);   // 512x1024      (1 MiB)
  float* pbuf = (float*)(ws + 28 * MiB);   // 32768x16 f32  (2 MiB)
  short* ubuf = (short*)(ws + 30 * MiB);   // 2048x8x2048   (64 MiB)
  short* Hbf  = (short*)(ws + 94 * MiB);   // 32768x2048    (128 MiB)

  // 1. fused prep: build_av + 5 transposes + LN
  prep_kernel<<<9728, 256, 0, stream>>>(A, V, avbf, Wk, WkT, Wv, WvT, Wq, WqT,
                                        W1, W1T, W2, W2T, S, gamma, beta, Snbf);

  // 2. fused K+V (split) + Q projections
  gemm_kvq<<<288, 256, 0, stream>>>(avbf, WkT, bk, bv, kbf, vbf, Snbf, WqT, bq, qbf);

  // 3. merged: u-GEMM (2048 blocks) + attention softmax (512 blocks)
  u_attn_kernel<<<2560, 256, 0, stream>>>(vbf, W1T, ubuf, qbf, kbf, pbuf);

  // 4. H = relu(sum p*u + b1)
  mix_kernel<<<1024, 512, 0, stream>>>(ubuf, pbuf, b1, Hbf);

  // 5. FFN2: out = H @ W2 + b2 (fp32 out) — 256x128 tile, BK=32, 2 blocks/CU
  gemm256<0, 0, 1><<<dim3(8, 128), 512, 0, stream>>>(Hbf, 2048, W2T, 2048, b2,
                                                     (float*)d_out, 1024, 2048);
}

// Round 12
// 290.398 us; speedup vs baseline: 4.5915x; 1.0720x over previous
//
#include <hip/hip_runtime.h>
#include <hip/hip_bf16.h>

// Shapes
#define BSZ 16
#define NSEG 64
#define NSEN 32
#define DM 1024
#define NH 8
#define DKH 128
#define DFF 2048

typedef short bf16x8 __attribute__((ext_vector_type(8)));
typedef float f32x4 __attribute__((ext_vector_type(4)));

__device__ __forceinline__ float b2f(short u) {
  union { unsigned int i; float f; } c;
  c.i = ((unsigned int)(unsigned short)u) << 16;
  return c.f;
}
__device__ __forceinline__ short f2b(float f) {
  __hip_bfloat16 h = __float2bfloat16(f);
  return *reinterpret_cast<short*>(&h);
}

#define SCHED0 __builtin_amdgcn_sched_barrier(0)
#define BAR do { SCHED0; __builtin_amdgcn_s_barrier(); SCHED0; } while (0)

// ================= fused prep: build_av + 5 weight transposes + LN =================
__device__ __forceinline__ void transpose_body(const float* __restrict__ W,
                                               short* __restrict__ Wt,
                                               int K, int N, int bx, int by,
                                               float* tile /*32*33*/) {
  int tx = threadIdx.x & 31, ty = threadIdx.x >> 5;
  int n0 = bx * 32, k0 = by * 32;
#pragma unroll
  for (int i = 0; i < 32; i += 8)
    tile[(ty + i) * 33 + tx] = W[(size_t)(k0 + ty + i) * N + n0 + tx];
  __syncthreads();
#pragma unroll
  for (int i = 0; i < 32; i += 8)
    Wt[(size_t)(n0 + ty + i) * K + k0 + tx] = f2b(tile[tx * 33 + ty + i]);
}

__global__ __launch_bounds__(256) void prep_kernel(
    const float* __restrict__ A, const float* __restrict__ V, short* __restrict__ avbf,
    const float* __restrict__ Wk, short* __restrict__ WkT,
    const float* __restrict__ Wv, short* __restrict__ WvT,
    const float* __restrict__ Wq, short* __restrict__ WqT,
    const float* __restrict__ W1, short* __restrict__ W1T,
    const float* __restrict__ W2, short* __restrict__ W2T,
    const float* __restrict__ S, const float* __restrict__ gamma,
    const float* __restrict__ beta, short* __restrict__ Snbf) {
  __shared__ float smem[32 * 33];
  int bid = blockIdx.x;
  int t = threadIdx.x;
  if (bid < 2048) {
    int i = bid * 256 + t;
    size_t o = (size_t)i * 4;
    int r = (int)(o >> 10);
    int d = (int)(o & 1023);
    int m = r & 1;
    int bseg = r >> 1;
    const float* src = (m ? V : A) + (size_t)bseg * 1024 + d;
    float4 v = *(const float4*)src;
    short4 out;
    out.x = f2b(v.x); out.y = f2b(v.y); out.z = f2b(v.z); out.w = f2b(v.w);
    *(short4*)(avbf + o) = out;
  } else if (bid < 3072) {
    int id = bid - 2048;
    transpose_body(Wk, WkT, 1024, 1024, id & 31, id >> 5, smem);
  } else if (bid < 4096) {
    int id = bid - 3072;
    transpose_body(Wv, WvT, 1024, 1024, id & 31, id >> 5, smem);
  } else if (bid < 5120) {
    int id = bid - 4096;
    transpose_body(Wq, WqT, 1024, 1024, id & 31, id >> 5, smem);
  } else if (bid < 7168) {
    int id = bid - 5120;
    transpose_body(W1, W1T, 1024, 2048, id & 63, id >> 6, smem);
  } else if (bid < 9216) {
    int id = bid - 7168;
    transpose_body(W2, W2T, 2048, 1024, id & 31, id >> 5, smem);
  } else {
    int row = bid - 9216;
    int l = t & 63, w = t >> 6;
    const float* x = S + (size_t)row * 1024;
    float4 v = ((const float4*)x)[t];
    float s = v.x + v.y + v.z + v.w;
#pragma unroll
    for (int off = 32; off; off >>= 1) s += __shfl_down(s, off);
    if (l == 0) smem[w] = s;
    __syncthreads();
    if (t == 0) smem[4] = (smem[0] + smem[1] + smem[2] + smem[3]) * (1.0f / 1024.0f);
    __syncthreads();
    float mean = smem[4];
    float4 c = {v.x - mean, v.y - mean, v.z - mean, v.w - mean};
    float s2 = c.x * c.x + c.y * c.y + c.z * c.z + c.w * c.w;
#pragma unroll
    for (int off = 32; off; off >>= 1) s2 += __shfl_down(s2, off);
    __syncthreads();
    if (l == 0) smem[w] = s2;
    __syncthreads();
    if (t == 0) smem[5] = (smem[0] + smem[1] + smem[2] + smem[3]) * (1.0f / 1024.0f);
    __syncthreads();
    float rstd = rsqrtf(smem[5] + 1e-5f);
    int base = t * 4;
    short4 o;
    o.x = f2b(c.x * rstd * gamma[base + 0] + beta[base + 0]);
    o.y = f2b(c.y * rstd * gamma[base + 1] + beta[base + 1]);
    o.z = f2b(c.z * rstd * gamma[base + 2] + beta[base + 2]);
    o.w = f2b(c.w * rstd * gamma[base + 3] + beta[base + 3]);
    *(short4*)(Snbf + (size_t)row * 1024 + base) = o;
  }
}

// ================ fused KV + Q projections (m97 128x128 body, K=1024) ================
__global__ __launch_bounds__(256) void gemm_kvq(const short* __restrict__ avbf,
                                                const short* __restrict__ WkvT,
                                                const float* __restrict__ bk,
                                                const float* __restrict__ bv,
                                                short* __restrict__ kbf,
                                                short* __restrict__ vbf,
                                                const short* __restrict__ Snbf,
                                                const short* __restrict__ WqT,
                                                const float* __restrict__ bq,
                                                short* __restrict__ qbf) {
  constexpr int BK = 32;
  __shared__ short As[128 * BK];
  __shared__ short Bs[128 * BK];
  int bid = blockIdx.x;
  const short *Ab, *Bb;
  const float *biasLo, *biasHi;
  short *Clo, *Chi;
  int bm, bn;
  bool split;
  if (bid < 256) {
    int nb = (bid & 7) * 32 + (bid >> 3);
    bn = nb & 15; bm = nb >> 4;
    Ab = avbf; Bb = WkvT; biasLo = bk; biasHi = bv; Clo = kbf; Chi = vbf; split = true;
  } else {
    int id = bid - 256;
    bm = id >> 3; bn = id & 7;
    Ab = Snbf; Bb = WqT; biasLo = bq; biasHi = bq; Clo = qbf; Chi = qbf; split = false;
  }

  const int t = threadIdx.x, w = t >> 6, l = t & 63;
  const int wm = w >> 1, wn = w & 1;
  f32x4 acc[4][4] = {};
  const size_t brow = (size_t)bm * 128, bcol = (size_t)bn * 128;

  for (int kt = 0; kt < 1024; kt += BK) {
#pragma unroll
    for (int i = 0; i < 2; i++) {
      int s = w * 128 + i * 64 + l;
      int row = s >> 2, c = (s & 3) * 8;
      const short* ga = Ab + (brow + row) * (size_t)1024 + kt + c;
      __builtin_amdgcn_global_load_lds(
          (const __attribute__((address_space(1))) unsigned int*)ga,
          (__attribute__((address_space(3))) unsigned int*)(As + (w * 128 + i * 64) * 8),
          16, 0, 0);
      const short* gb = Bb + (bcol + row) * (size_t)1024 + kt + c;
      __builtin_amdgcn_global_load_lds(
          (const __attribute__((address_space(1))) unsigned int*)gb,
          (__attribute__((address_space(3))) unsigned int*)(Bs + (w * 128 + i * 64) * 8),
          16, 0, 0);
    }
    __syncthreads();
    bf16x8 af[4], bfr[4];
#pragma unroll
    for (int mi = 0; mi < 4; mi++)
      af[mi] = *(const bf16x8*)(As + (wm * 64 + mi * 16 + (l & 15)) * BK + (l >> 4) * 8);
#pragma unroll
    for (int ni = 0; ni < 4; ni++)
      bfr[ni] = *(const bf16x8*)(Bs + (wn * 64 + ni * 16 + (l & 15)) * BK + (l >> 4) * 8);
#pragma unroll
    for (int mi = 0; mi < 4; mi++)
#pragma unroll
      for (int ni = 0; ni < 4; ni++)
        acc[mi][ni] = __builtin_amdgcn_mfma_f32_16x16x32_bf16(af[mi], bfr[ni], acc[mi][ni], 0, 0, 0);
    __syncthreads();
  }

  const int lr = (l >> 4) * 4, lc = l & 15;
#pragma unroll
  for (int mi = 0; mi < 4; mi++) {
#pragma unroll
    for (int ni = 0; ni < 4; ni++) {
      size_t gcol = bcol + wn * 64 + ni * 16 + lc;
      int half = split ? (gcol >= 1024) : 0;
      size_t cc = half ? (gcol - 1024) : gcol;
      const float* bp = half ? biasHi : biasLo;
      short* op = half ? Chi : Clo;
      float bvv = bp[cc];
#pragma unroll
      for (int r = 0; r < 4; r++) {
        size_t grow = brow + wm * 64 + mi * 16 + lr + r;
        op[grow * 1024 + cc] = f2b(acc[mi][ni][r] + bvv);
      }
    }
  }
}

// ========== merged u-GEMM + attention-softmax dispatch ==========
__global__ __launch_bounds__(256) void u_attn_kernel(const short* __restrict__ vbf,
                                                     const short* __restrict__ W1T,
                                                     short* __restrict__ ubuf,
                                                     const short* __restrict__ qbf,
                                                     const short* __restrict__ kbf,
                                                     float* __restrict__ p) {
  __shared__ short smem[8192];
  int bid = blockIdx.x;
  int t = threadIdx.x;
  if (bid < 2048) {
    constexpr int BK = 32;
    short* As = smem;
    short* Bs = smem + 4096;
    int h = bid >> 8;
    int L = bid & 255;
    int nb = (L & 7) * 32 + (L >> 3);
    int bn = nb & 15, bm = nb >> 4;
    const short* Ab = vbf + h * 128;
    const short* Bb = W1T + h * 128;
    short* Cb = ubuf + h * 2048;

    const int w = t >> 6, l = t & 63;
    const int wm = w >> 1, wn = w & 1;
    f32x4 acc[4][4] = {};
    const size_t brow = (size_t)bm * 128, bcol = (size_t)bn * 128;

    for (int kt = 0; kt < 128; kt += BK) {
#pragma unroll
      for (int i = 0; i < 2; i++) {
        int s = w * 128 + i * 64 + l;
        int row = s >> 2, c = (s & 3) * 8;
        const short* ga = Ab + (brow + row) * (size_t)1024 + kt + c;
        __builtin_amdgcn_global_load_lds(
            (const __attribute__((address_space(1))) unsigned int*)ga,
            (__attribute__((address_space(3))) unsigned int*)(As + (w * 128 + i * 64) * 8),
            16, 0, 0);
        const short* gb = Bb + (bcol + row) * (size_t)1024 + kt + c;
        __builtin_amdgcn_global_load_lds(
            (const __attribute__((address_space(1))) unsigned int*)gb,
            (__attribute__((address_space(3))) unsigned int*)(Bs + (w * 128 + i * 64) * 8),
            16, 0, 0);
      }
      __syncthreads();
      bf16x8 af[4], bfr[4];
#pragma unroll
      for (int mi = 0; mi < 4; mi++)
        af[mi] = *(const bf16x8*)(As + (wm * 64 + mi * 16 + (l & 15)) * BK + (l >> 4) * 8);
#pragma unroll
      for (int ni = 0; ni < 4; ni++)
        bfr[ni] = *(const bf16x8*)(Bs + (wn * 64 + ni * 16 + (l & 15)) * BK + (l >> 4) * 8);
#pragma unroll
      for (int mi = 0; mi < 4; mi++)
#pragma unroll
        for (int ni = 0; ni < 4; ni++)
          acc[mi][ni] = __builtin_amdgcn_mfma_f32_16x16x32_bf16(af[mi], bfr[ni], acc[mi][ni], 0, 0, 0);
      __syncthreads();
    }

    const int lr = (l >> 4) * 4, lc = l & 15;
#pragma unroll
    for (int mi = 0; mi < 4; mi++) {
#pragma unroll
      for (int ni = 0; ni < 4; ni++) {
        size_t gcol = bcol + wn * 64 + ni * 16 + lc;
#pragma unroll
        for (int r = 0; r < 4; r++) {
          size_t grow = brow + wm * 64 + mi * 16 + lr + r;
          Cb[grow * 16384 + gcol] = f2b(acc[mi][ni][r]);
        }
      }
    }
  } else {
    int blk = bid - 2048;  // b*32+sen
    int b = blk >> 5;
    float* qs = (float*)smem;
    float* ss = ((float*)smem) + 1024;
    {
      short4 qv = *(const short4*)(qbf + (size_t)blk * 1024 + t * 4);
      qs[t * 4 + 0] = b2f(qv.x);
      qs[t * 4 + 1] = b2f(qv.y);
      qs[t * 4 + 2] = b2f(qv.z);
      qs[t * 4 + 3] = b2f(qv.w);
    }
    __syncthreads();
    float sc[4];
#pragma unroll
    for (int i = 0; i < 4; i++) {
      int idx = i * 256 + t;
      int seg = idx >> 4, h = (idx >> 1) & 7, m = idx & 1;
      const short* kp = kbf + ((size_t)((b * 64 + seg) * 2 + m)) * 1024 + h * 128;
      float s = 0.f;
#pragma unroll
      for (int j = 0; j < 16; j++) {
        bf16x8 kv = *(const bf16x8*)(kp + j * 8);
#pragma unroll
        for (int e = 0; e < 8; e++) s += qs[h * 128 + j * 8 + e] * b2f(kv[e]);
      }
      sc[i] = s * 0.08838834764831845f;
    }
#pragma unroll
    for (int i = 0; i < 4; i++) ss[i * 256 + t] = sc[i];
    __syncthreads();
    for (int i = t; i < 512; i += 256) {
      float s0 = ss[2 * i], s1 = ss[2 * i + 1];
      float mx = fmaxf(s0, s1);
      float e0 = __expf(s0 - mx), e1 = __expf(s1 - mx);
      float inv = 1.f / (e0 + e1);
      int seg = i >> 3, h = i & 7;
      size_t base = (size_t)blk * 1024 + seg * 16;
      p[base + h] = e0 * inv;
      p[base + 8 + h] = e1 * inv;
    }
  }
}

// ---------------- 256x256 bf16 GEMM: r9 trimmed-barrier schedule (best known) -------
// Depth-2 prefetch (stage B@P2-equiv, A@P3-equiv), counted vmcnt(8) once per K-tile,
// 3 barriers per K-tile, XOR swizzle via pre-swizzled global source, setprio on MFMA.
template <int RELU, int OUTBF, int BIAS>
__global__ __launch_bounds__(512, 2) void gemm256(const short* __restrict__ Abf, int lda,
                                                  const short* __restrict__ Btbf, int ldb,
                                                  const float* __restrict__ bias,
                                                  void* __restrict__ Cout, int ldc, int K) {
  __shared__ __align__(16) short As[2][256 * 64];
  __shared__ __align__(16) short Bs[2][256 * 64];
  const int t = threadIdx.x;
  const int w = t >> 6, l = t & 63;
  const int wr = w >> 2, wc = w & 3;       // 2 x 4 wave grid
  const int l15 = l & 15, lhi = l >> 4;

  int nwg = gridDim.x * gridDim.y;
  int L = blockIdx.y * gridDim.x + blockIdx.x;
  int bm, bn;
  if ((nwg & 7) == 0) {
    int cpx = nwg >> 3;
    int nb = (L & 7) * cpx + (L >> 3);
    bn = nb % gridDim.x;
    bm = nb / gridDim.x;
  } else {
    bn = blockIdx.x;
    bm = blockIdx.y;
  }
  const size_t brow = (size_t)bm * 256, bcol = (size_t)bn * 256;
  const int NT = K >> 6;

  auto stage = [&](short* dst, const short* src, int ld, size_t rowoff, int kt) {
#pragma unroll
    for (int i = 0; i < 4; ++i) {
      int seg = i * 512 + t;
      int row = seg >> 3, s = seg & 7;
      const short* g = src + (rowoff + row) * (size_t)ld + kt + ((s ^ (row & 7)) << 3);
      __builtin_amdgcn_global_load_lds(
          (const __attribute__((address_space(1))) unsigned int*)g,
          (__attribute__((address_space(3))) unsigned int*)(dst + seg * 8),
          16, 0, 0);
    }
  };
  auto rdA = [&](const short* base, int m, int kk) -> bf16x8 {
    int r = wr * 128 + m * 16 + l15;
    int d = kk * 4 + lhi;
    return *(const bf16x8*)(base + (r << 6) + ((d ^ (r & 7)) << 3));
  };
  auto rdB = [&](const short* base, int n, int kk) -> bf16x8 {
    int r = wc * 64 + n * 16 + l15;
    int d = kk * 4 + lhi;
    return *(const bf16x8*)(base + (r << 6) + ((d ^ (r & 7)) << 3));
  };

  f32x4 acc[8][4] = {};
  bf16x8 afr[4][2], bfr[4][2];

  // Prologue: stage K-tiles 0 and 1; wait only for tile 0 (counted vmcnt).
  stage(Bs[0], Btbf, ldb, bcol, 0);
  stage(As[0], Abf, lda, brow, 0);
  stage(Bs[1], Btbf, ldb, bcol, 64);
  stage(As[1], Abf, lda, brow, 64);
  asm volatile("s_waitcnt vmcnt(8)" ::: "memory");
  BAR;

  for (int T = 0; T < NT; ++T) {
    const short* Ab = As[T & 1];
    const short* Bb = Bs[T & 1];
    short* Aw = (short*)As[T & 1];
    short* Bw = (short*)Bs[T & 1];
    const int ktn = (T + 2) * 64;
    const bool st = (T + 2) < NT;

    // ---- P0+P1 (no internal barriers): reads + MFMA m0-3 x all n ----
#pragma unroll
    for (int m = 0; m < 4; ++m) { afr[m][0] = rdA(Ab, m, 0); afr[m][1] = rdA(Ab, m, 1); }
#pragma unroll
    for (int n = 0; n < 2; ++n) { bfr[n][0] = rdB(Bb, n, 0); bfr[n][1] = rdB(Bb, n, 1); }
    __builtin_amdgcn_s_setprio(1);
#pragma unroll
    for (int m = 0; m < 4; ++m)
#pragma unroll
      for (int n = 0; n < 2; ++n) {
        acc[m][n] = __builtin_amdgcn_mfma_f32_16x16x32_bf16(afr[m][0], bfr[n][0], acc[m][n], 0, 0, 0);
        acc[m][n] = __builtin_amdgcn_mfma_f32_16x16x32_bf16(afr[m][1], bfr[n][1], acc[m][n], 0, 0, 0);
      }
    __builtin_amdgcn_s_setprio(0);
#pragma unroll
    for (int n = 2; n < 4; ++n) { bfr[n][0] = rdB(Bb, n, 0); bfr[n][1] = rdB(Bb, n, 1); }
    __builtin_amdgcn_s_setprio(1);
#pragma unroll
    for (int m = 0; m < 4; ++m)
#pragma unroll
      for (int n = 2; n < 4; ++n) {
        acc[m][n] = __builtin_amdgcn_mfma_f32_16x16x32_bf16(afr[m][0], bfr[n][0], acc[m][n], 0, 0, 0);
        acc[m][n] = __builtin_amdgcn_mfma_f32_16x16x32_bf16(afr[m][1], bfr[n][1], acc[m][n], 0, 0, 0);
      }
    __builtin_amdgcn_s_setprio(0);
    BAR;  // all B-buffer reads drained (P1 MFMA waited on them) -> B overwrite safe

    // ---- P2: stage next-next B ; read A m4-7 ; MFMA m4-7 x n0-1 ----
    if (st) stage(Bw, Btbf, ldb, bcol, ktn);
#pragma unroll
    for (int m = 0; m < 4; ++m) { afr[m][0] = rdA(Ab, m + 4, 0); afr[m][1] = rdA(Ab, m + 4, 1); }
    __builtin_amdgcn_s_setprio(1);
#pragma unroll
    for (int m = 0; m < 4; ++m)
#pragma unroll
      for (int n = 0; n < 2; ++n) {
        acc[m + 4][n] = __builtin_amdgcn_mfma_f32_16x16x32_bf16(afr[m][0], bfr[n][0], acc[m + 4][n], 0, 0, 0);
        acc[m + 4][n] = __builtin_amdgcn_mfma_f32_16x16x32_bf16(afr[m][1], bfr[n][1], acc[m + 4][n], 0, 0, 0);
      }
    __builtin_amdgcn_s_setprio(0);
    BAR;  // all A-buffer reads drained (P2 MFMA waited on them) -> A overwrite safe

    // ---- P3: stage next-next A ; MFMA m4-7 x n2-3 ; counted vmcnt per K-tile ----
    if (st) stage(Aw, Abf, lda, brow, ktn);
    __builtin_amdgcn_s_setprio(1);
#pragma unroll
    for (int m = 0; m < 4; ++m)
#pragma unroll
      for (int n = 2; n < 4; ++n) {
        acc[m + 4][n] = __builtin_amdgcn_mfma_f32_16x16x32_bf16(afr[m][0], bfr[n][0], acc[m + 4][n], 0, 0, 0);
        acc[m + 4][n] = __builtin_amdgcn_mfma_f32_16x16x32_bf16(afr[m][1], bfr[n][1], acc[m + 4][n], 0, 0, 0);
      }
    __builtin_amdgcn_s_setprio(0);
    if (st) { asm volatile("s_waitcnt vmcnt(8)" ::: "memory"); }
    else    { asm volatile("s_waitcnt vmcnt(0)" ::: "memory"); }
    BAR;  // T+1 data certified for next-tile reads
  }

  // ---- Epilogue ----
#pragma unroll
  for (int m = 0; m < 8; ++m) {
#pragma unroll
    for (int n = 0; n < 4; ++n) {
      size_t col = bcol + wc * 64 + n * 16 + l15;
      float bvv = BIAS ? bias[col] : 0.f;
#pragma unroll
      for (int r = 0; r < 4; ++r) {
        size_t row = brow + wr * 128 + m * 16 + lhi * 4 + r;
        float val = acc[m][n][r] + bvv;
        if (RELU) val = fmaxf(val, 0.f);
        if (OUTBF)
          ((short*)Cout)[row * (size_t)ldc + col] = f2b(val);
        else
          ((float*)Cout)[row * (size_t)ldc + col] = val;
      }
    }
  }
}

// ---------------- mix: H[row,f] = relu(sum_{m,h} p*u + b1) ----------------
__global__ __launch_bounds__(512) void mix_kernel(const short* __restrict__ u,
                                                  const float* __restrict__ p,
                                                  const float* __restrict__ b1,
                                                  short* __restrict__ H) {
  int blk = blockIdx.x;  // b*64+seg
  int b = blk >> 6, seg = blk & 63;
  int t = threadIdx.x;
  __shared__ float ps[512];
  {
    int sen = t >> 4, j = t & 15;
    ps[t] = p[(size_t)(b * 32 + sen) * 1024 + seg * 16 + j];
  }
  int f0 = t * 4;
  float ur[16][4];
#pragma unroll
  for (int mh = 0; mh < 16; ++mh) {
    int m = mh >> 3, h = mh & 7;
    const short* up = u + ((size_t)(blk * 2 + m)) * 16384 + h * 2048 + f0;
    short4 uv = *(const short4*)up;
    ur[mh][0] = b2f(uv.x); ur[mh][1] = b2f(uv.y);
    ur[mh][2] = b2f(uv.z); ur[mh][3] = b2f(uv.w);
  }
  float4 bb = *(const float4*)(b1 + f0);
  __syncthreads();
  for (int sen = 0; sen < 32; ++sen) {
    float a0 = bb.x, a1 = bb.y, a2 = bb.z, a3 = bb.w;
#pragma unroll
    for (int mh = 0; mh < 16; ++mh) {
      float wv = ps[sen * 16 + mh];
      a0 += wv * ur[mh][0];
      a1 += wv * ur[mh][1];
      a2 += wv * ur[mh][2];
      a3 += wv * ur[mh][3];
    }
    short4 o;
    o.x = f2b(fmaxf(a0, 0.f));
    o.y = f2b(fmaxf(a1, 0.f));
    o.z = f2b(fmaxf(a2, 0.f));
    o.w = f2b(fmaxf(a3, 0.f));
    size_t row = (size_t)(b * 32 + sen) * 64 + seg;
    *(short4*)(H + row * 2048 + f0) = o;
  }
}

extern "C" void kernel_launch(void* const* d_in, const int* in_sizes, int n_in,
                              void* d_out, int out_size, void* d_ws, size_t ws_size,
                              hipStream_t stream) {
  const float* A = (const float*)d_in[0];
  const float* V = (const float*)d_in[1];
  const float* S = (const float*)d_in[2];
  const float* Wq = (const float*)d_in[3];
  const float* bq = (const float*)d_in[4];
  const float* Wk = (const float*)d_in[5];
  const float* bk = (const float*)d_in[6];
  const float* Wv = (const float*)d_in[7];
  const float* bv = (const float*)d_in[8];
  const float* gamma = (const float*)d_in[9];
  const float* beta = (const float*)d_in[10];
  const float* W1 = (const float*)d_in[11];
  const float* b1 = (const float*)d_in[12];
  const float* W2 = (const float*)d_in[13];
  const float* b2 = (const float*)d_in[14];

  const size_t MiB = 1048576;
  char* ws = (char*)d_ws;
  short* avbf = (short*)(ws + 0 * MiB);    // 2048x1024 bf16 (4 MiB)
  short* WkT  = (short*)(ws + 4 * MiB);    // 1024x1024     (2 MiB)  } adjacent: merged KV B
  short* WvT  = (short*)(ws + 6 * MiB);    // 1024x1024     (2 MiB)  }
  short* WqT  = (short*)(ws + 8 * MiB);    // 1024x1024     (2 MiB)
  short* W1T  = (short*)(ws + 10 * MiB);   // 2048x1024     (4 MiB)
  short* W2T  = (short*)(ws + 14 * MiB);   // 1024x2048     (4 MiB)
  short* Snbf = (short*)(ws + 18 * MiB);   // 512x1024      (1 MiB)
  short* kbf  = (short*)(ws + 19 * MiB);   // 2048x1024     (4 MiB)
  short* vbf  = (short*)(ws + 23 * MiB);   // 2048x1024     (4 MiB)
  short* qbf  = (short*)(ws + 27 * MiB);   // 512x1024      (1 MiB)
  float* pbuf = (float*)(ws + 28 * MiB);   // 32768x16 f32  (2 MiB)
  short* ubuf = (short*)(ws + 30 * MiB);   // 2048x8x2048   (64 MiB)
  short* Hbf  = (short*)(ws + 94 * MiB);   // 32768x2048    (128 MiB)

  // 1. fused prep: build_av + 5 transposes + LN
  prep_kernel<<<9728, 256, 0, stream>>>(A, V, avbf, Wk, WkT, Wv, WvT, Wq, WqT,
                                        W1, W1T, W2, W2T, S, gamma, beta, Snbf);

  // 2. fused K+V (split) + Q projections
  gemm_kvq<<<288, 256, 0, stream>>>(avbf, WkT, bk, bv, kbf, vbf, Snbf, WqT, bq, qbf);

  // 3. merged: u-GEMM (2048 blocks) + attention softmax (512 blocks)
  u_attn_kernel<<<2560, 256, 0, stream>>>(vbf, W1T, ubuf, qbf, kbf, pbuf);

  // 4. H = relu(sum p*u + b1)
  mix_kernel<<<1024, 512, 0, stream>>>(ubuf, pbuf, b1, Hbf);

  // 5. FFN2: out = H @ W2 + b2 (fp32 out) — 256^2, trimmed-barrier schedule (r9 best)
  gemm256<0, 0, 1><<<dim3(4, 128), 512, 0, stream>>>(Hbf, 2048, W2T, 2048, b2,
                                                     (float*)d_out, 1024, 2048);
}